// Round 1
// baseline (470.474 us; speedup 1.0000x reference)
//
#include <hip/hip_runtime.h>
#include <math.h>

#define N_NODES 100000
#define N_EDGES 1600000

// ws layout (bytes)
#define OFF_CNT    0x0u          // int[100000]
#define OFF_START  0x80000u      // int[100000]
#define OFF_CURSOR 0x100000u     // int[100000]
#define OFF_DIS    0x180000u     // float[100000]
#define OFF_BSUM   0x200000u     // int[512]
#define OFF_BOFF   0x201000u     // int[512]
#define OFF_FLAG   0x202000u     // int[1]
#define OFF_SRCS   0x280000u     // int[1600000]
#define OFF_HS     0x900000u     // float[12800000]  (ends 60,637,184)
#define OFF_ACC    0x3A00000u    // float[12800000]  (ends ~112 MB)

// ---- edge dtype detect: int64 edge_index has zero high words ----
__global__ void k_detect(const int* __restrict__ p32, int* __restrict__ flag) {
  __shared__ int nz;
  if (threadIdx.x == 0) nz = 0;
  __syncthreads();
  if (p32[2 * threadIdx.x + 1] != 0) atomicAdd(&nz, 1);
  __syncthreads();
  if (threadIdx.x == 0) *flag = (nz == 0) ? 1 : 0;  // 1 => int64 (stride 2)
}

__global__ void k_zero(int* __restrict__ cnt) {
  int i = blockIdx.x * 256 + threadIdx.x;
  if (i < N_NODES) cnt[i] = 0;
}

__global__ void k_count(const int* __restrict__ p32, const int* __restrict__ flag,
                        int* __restrict__ cnt) {
  int e = blockIdx.x * 256 + threadIdx.x;
  if (e >= N_EDGES) return;
  int s = *flag;
  int c = p32[((size_t)(N_EDGES + e)) << s];
  atomicAdd(&cnt[c], 1);
}

__global__ void k_scan1(const int* __restrict__ cnt, int* __restrict__ startp,
                        int* __restrict__ bsum) {
  __shared__ int sm[256];
  int t = threadIdx.x;
  int i = blockIdx.x * 256 + t;
  int v = (i < N_NODES) ? cnt[i] : 0;
  sm[t] = v;
  __syncthreads();
  for (int off = 1; off < 256; off <<= 1) {
    int xv = (t >= off) ? sm[t - off] : 0;
    __syncthreads();
    sm[t] += xv;
    __syncthreads();
  }
  if (i < N_NODES) startp[i] = sm[t] - v;  // exclusive
  if (t == 255) bsum[blockIdx.x] = sm[255];
}

__global__ void k_scan2(const int* __restrict__ bsum, int* __restrict__ boff, int nblk) {
  __shared__ int sm[512];
  int t = threadIdx.x;
  int v = (t < nblk) ? bsum[t] : 0;
  sm[t] = v;
  __syncthreads();
  for (int off = 1; off < 512; off <<= 1) {
    int xv = (t >= off) ? sm[t - off] : 0;
    __syncthreads();
    sm[t] += xv;
    __syncthreads();
  }
  if (t < nblk) boff[t] = sm[t] - v;  // exclusive
}

__global__ void k_scan3(int* __restrict__ startp, int* __restrict__ cursor,
                        const int* __restrict__ boff) {
  int i = blockIdx.x * 256 + threadIdx.x;
  if (i < N_NODES) {
    int v = startp[i] + boff[blockIdx.x];
    startp[i] = v;
    cursor[i] = v;
  }
}

__global__ void k_dis(const int* __restrict__ cnt, float* __restrict__ dis) {
  int i = blockIdx.x * 256 + threadIdx.x;
  if (i < N_NODES) dis[i] = rsqrtf((float)cnt[i] + 1.0f);  // +1 self-loop
}

__global__ void k_place(const int* __restrict__ p32, const int* __restrict__ flag,
                        int* __restrict__ cursor, int* __restrict__ srcs) {
  int e = blockIdx.x * 256 + threadIdx.x;
  if (e >= N_EDGES) return;
  int s = *flag;
  int r = p32[((size_t)e) << s];
  int c = p32[((size_t)(N_EDGES + e)) << s];
  int pos = atomicAdd(&cursor[c], 1);
  srcs[pos] = r;
}

// hs[n] = dis[n] * (x @ W1)[n]   -- 64 rows/block, thread = 4 rows x 8 cols
__global__ __launch_bounds__(256) void k_gemm1(
    const float* __restrict__ x, const float* __restrict__ W,
    const float* __restrict__ dis, float* __restrict__ hs) {
  __shared__ float xs[64][132];      // +4 pad breaks stride-128 bank aliasing
  __shared__ float wsm[128 * 128];
  const int t = threadIdx.x;
  const int row0 = blockIdx.x * 64;
#pragma unroll
  for (int i = 0; i < 16; ++i) {
    int lin = i * 256 + t;
    ((float4*)wsm)[lin] = ((const float4*)W)[lin];
  }
#pragma unroll
  for (int i = 0; i < 8; ++i) {
    int lin = i * 256 + t;
    int r = lin >> 5, c4 = lin & 31;
    int gr = row0 + r;
    float4 v = make_float4(0.f, 0.f, 0.f, 0.f);
    if (gr < N_NODES) v = *(const float4*)(x + (size_t)gr * 128 + c4 * 4);
    xs[r][c4 * 4 + 0] = v.x; xs[r][c4 * 4 + 1] = v.y;
    xs[r][c4 * 4 + 2] = v.z; xs[r][c4 * 4 + 3] = v.w;
  }
  __syncthreads();
  const int ty = t >> 4, tx = t & 15;
  float acc[4][8];
#pragma unroll
  for (int i = 0; i < 4; ++i)
#pragma unroll
    for (int j = 0; j < 8; ++j) acc[i][j] = 0.f;
#pragma unroll 4
  for (int k = 0; k < 128; ++k) {
    float xv[4];
#pragma unroll
    for (int i = 0; i < 4; ++i) xv[i] = xs[ty * 4 + i][k];
    float4 wa = *(const float4*)&wsm[k * 128 + tx * 8];
    float4 wb = *(const float4*)&wsm[k * 128 + tx * 8 + 4];
    float wv[8] = {wa.x, wa.y, wa.z, wa.w, wb.x, wb.y, wb.z, wb.w};
#pragma unroll
    for (int i = 0; i < 4; ++i)
#pragma unroll
      for (int j = 0; j < 8; ++j) acc[i][j] = fmaf(xv[i], wv[j], acc[i][j]);
  }
#pragma unroll
  for (int i = 0; i < 4; ++i) {
    int r = row0 + ty * 4 + i;
    if (r >= N_NODES) continue;
    float d = dis[r];
    float4 o0 = make_float4(acc[i][0] * d, acc[i][1] * d, acc[i][2] * d, acc[i][3] * d);
    float4 o1 = make_float4(acc[i][4] * d, acc[i][5] * d, acc[i][6] * d, acc[i][7] * d);
    *(float4*)(hs + (size_t)r * 128 + tx * 8) = o0;
    *(float4*)(hs + (size_t)r * 128 + tx * 8 + 4) = o1;
  }
}

// acc[n] = dis[n] * (hs[n] + sum_{incoming} hs[src]) + b1   -- 32 lanes/node
__global__ __launch_bounds__(256) void k_agg(
    const float* __restrict__ hs, const int* __restrict__ startp,
    const int* __restrict__ cnt, const int* __restrict__ srcs,
    const float* __restrict__ dis, const float* __restrict__ b1,
    float* __restrict__ acc) {
  const int t = threadIdx.x;
  const int g = t >> 5, lane = t & 31;
  const int n = blockIdx.x * 8 + g;
  if (n >= N_NODES) return;
  float4 sum = *(const float4*)(hs + (size_t)n * 128 + lane * 4);  // self-loop
  const int s0 = startp[n];
  const int e0 = s0 + cnt[n];
  for (int j = s0; j < e0; ++j) {
    int src = srcs[j];
    float4 v = *(const float4*)(hs + (size_t)src * 128 + lane * 4);
    sum.x += v.x; sum.y += v.y; sum.z += v.z; sum.w += v.w;
  }
  float d = dis[n];
  float4 b = *(const float4*)(b1 + lane * 4);
  float4 o = make_float4(fmaf(d, sum.x, b.x), fmaf(d, sum.y, b.y),
                         fmaf(d, sum.z, b.z), fmaf(d, sum.w, b.w));
  *(float4*)(acc + (size_t)n * 128 + lane * 4) = o;
}

// out[n] = log_softmax(relu(acc[n]) @ linW + linb)   -- 4 lanes/node, 10 cols each
__global__ __launch_bounds__(256) void k_final(
    const float* __restrict__ acc, const float* __restrict__ linW,
    const float* __restrict__ linb, float* __restrict__ out) {
  __shared__ float vs[64][132];
  __shared__ float wl[128 * 40];
  __shared__ float lb[40];
  const int t = threadIdx.x;
  const int n0 = blockIdx.x * 64;
#pragma unroll
  for (int i = 0; i < 5; ++i) {
    int lin = i * 256 + t;
    ((float4*)wl)[lin] = ((const float4*)linW)[lin];
  }
  if (t < 40) lb[t] = linb[t];
#pragma unroll
  for (int i = 0; i < 8; ++i) {
    int lin = i * 256 + t;
    int r = lin >> 5, c4 = lin & 31;
    int n = n0 + r;
    float4 v = make_float4(0.f, 0.f, 0.f, 0.f);
    if (n < N_NODES) {
      v = *(const float4*)(acc + (size_t)n * 128 + c4 * 4);
      v.x = fmaxf(v.x, 0.f); v.y = fmaxf(v.y, 0.f);
      v.z = fmaxf(v.z, 0.f); v.w = fmaxf(v.w, 0.f);
    }
    vs[r][c4 * 4 + 0] = v.x; vs[r][c4 * 4 + 1] = v.y;
    vs[r][c4 * 4 + 2] = v.z; vs[r][c4 * 4 + 3] = v.w;
  }
  __syncthreads();
  const int nl = t >> 2, l4 = t & 3;
  const int n = n0 + nl;
  if (n >= N_NODES) return;
  float lg[10];
#pragma unroll
  for (int j = 0; j < 10; ++j) lg[j] = lb[l4 * 10 + j];
  for (int k = 0; k < 128; ++k) {
    float vk = vs[nl][k];
#pragma unroll
    for (int j = 0; j < 10; ++j) lg[j] = fmaf(vk, wl[k * 40 + l4 * 10 + j], lg[j]);
  }
  float m = lg[0];
#pragma unroll
  for (int j = 1; j < 10; ++j) m = fmaxf(m, lg[j]);
  m = fmaxf(m, __shfl_xor(m, 1));
  m = fmaxf(m, __shfl_xor(m, 2));
  float s = 0.f;
#pragma unroll
  for (int j = 0; j < 10; ++j) s += expf(lg[j] - m);
  s += __shfl_xor(s, 1);
  s += __shfl_xor(s, 2);
  float lse = m + logf(s);
#pragma unroll
  for (int j = 0; j < 10; ++j) out[(size_t)n * 40 + l4 * 10 + j] = lg[j] - lse;
}

extern "C" void kernel_launch(void* const* d_in, const int* in_sizes, int n_in,
                              void* d_out, int out_size, void* d_ws, size_t ws_size,
                              hipStream_t stream) {
  const float* x    = (const float*)d_in[0];
  const int*   ei   = (const int*)d_in[1];
  const float* W1   = (const float*)d_in[2];
  const float* b1   = (const float*)d_in[3];
  const float* linW = (const float*)d_in[4];
  const float* linb = (const float*)d_in[5];
  float* out = (float*)d_out;
  char* ws = (char*)d_ws;

  int*   cnt    = (int*)(ws + OFF_CNT);
  int*   startp = (int*)(ws + OFF_START);
  int*   cursor = (int*)(ws + OFF_CURSOR);
  float* dis    = (float*)(ws + OFF_DIS);
  int*   bsum   = (int*)(ws + OFF_BSUM);
  int*   boff   = (int*)(ws + OFF_BOFF);
  int*   flag   = (int*)(ws + OFF_FLAG);
  int*   srcs   = (int*)(ws + OFF_SRCS);
  float* hs     = (float*)(ws + OFF_HS);
  float* acc    = (float*)(ws + OFF_ACC);

  const int NBN = (N_NODES + 255) / 256;  // 391
  const int NBE = (N_EDGES + 255) / 256;  // 6250

  k_detect<<<1, 256, 0, stream>>>(ei, flag);
  k_zero<<<NBN, 256, 0, stream>>>(cnt);
  k_count<<<NBE, 256, 0, stream>>>(ei, flag, cnt);
  k_scan1<<<NBN, 256, 0, stream>>>(cnt, startp, bsum);
  k_scan2<<<1, 512, 0, stream>>>(bsum, boff, NBN);
  k_scan3<<<NBN, 256, 0, stream>>>(startp, cursor, boff);
  k_dis<<<NBN, 256, 0, stream>>>(cnt, dis);
  k_place<<<NBE, 256, 0, stream>>>(ei, flag, cursor, srcs);
  k_gemm1<<<(N_NODES + 63) / 64, 256, 0, stream>>>(x, W1, dis, hs);
  k_agg<<<(N_NODES + 7) / 8, 256, 0, stream>>>(hs, startp, cnt, srcs, dis, b1, acc);
  k_final<<<(N_NODES + 63) / 64, 256, 0, stream>>>(acc, linW, linb, out);
}